// Round 1
// 356.429 us; speedup vs baseline: 1.0715x; 1.0715x over previous
//
#include <hip/hip_runtime.h>

#define N_TOK 4096
#define DIM   1024
#define NE    8
#define CAP   1280
#define EC    (NE * CAP)           // 10240 floats per token per tensor
#define NEC   ((size_t)N_TOK * EC) // 41943040

// ---------------- Stage 1: logits -> softmax -> top2 ----------------
// One wave per token (4 waves / block). w_g (32 KB) staged in LDS.
__global__ __launch_bounds__(256) void k_logits(const float* __restrict__ x,
                                                const float* __restrict__ wg,
                                                int* __restrict__ top_idx,   // [2*N] k-major
                                                float* __restrict__ top_p) { // [2*N] k-major
    __shared__ float swg[NE * DIM];
    const float4* wg4 = (const float4*)wg;
    float4* swg4 = (float4*)swg;
#pragma unroll
    for (int i = 0; i < 8; ++i) {
        int t = i * 256 + threadIdx.x;
        swg4[t] = wg4[t];
    }
    __syncthreads();

    const int wave = threadIdx.x >> 6;
    const int lane = threadIdx.x & 63;
    const int token = blockIdx.x * 4 + wave;

    const float4* x4 = (const float4*)(x + (size_t)token * DIM);
    float acc[NE];
#pragma unroll
    for (int e = 0; e < NE; ++e) acc[e] = 0.f;

#pragma unroll
    for (int c = 0; c < 4; ++c) {
        float4 xv = x4[c * 64 + lane];
#pragma unroll
        for (int e = 0; e < NE; ++e) {
            float4 wv = swg4[e * 256 + c * 64 + lane];
            acc[e] += xv.x * wv.x + xv.y * wv.y + xv.z * wv.z + xv.w * wv.w;
        }
    }
#pragma unroll
    for (int e = 0; e < NE; ++e) {
        float v = acc[e];
#pragma unroll
        for (int off = 32; off > 0; off >>= 1)
            v += __shfl_xor(v, off, 64);
        acc[e] = v;
    }

    if (lane == 0) {
        float m = acc[0];
#pragma unroll
        for (int e = 1; e < NE; ++e) m = fmaxf(m, acc[e]);
        float pe[NE];
        float s = 0.f;
#pragma unroll
        for (int e = 0; e < NE; ++e) { pe[e] = expf(acc[e] - m); s += pe[e]; }
        float inv = 1.f / s;

        int i1 = 0; float v1 = acc[0];
#pragma unroll
        for (int e = 1; e < NE; ++e) if (acc[e] > v1) { v1 = acc[e]; i1 = e; }
        int i2 = (i1 == 0) ? 1 : 0; float v2 = acc[i2];
#pragma unroll
        for (int e = 0; e < NE; ++e)
            if (e != i1 && acc[e] > v2) { v2 = acc[e]; i2 = e; }

        top_idx[token]         = i1;
        top_idx[N_TOK + token] = i2;
        top_p[token]           = pe[i1] * inv;
        top_p[N_TOK + token]   = pe[i2] * inv;
    }
}

// ---------------- Stage 2: parallel rank in j = k*N+n order -------------------
// 256 threads x 32 contiguous items; emits per-assignment destination element
// dest[j] = e*CAP + rank (or -1 if over capacity). All per-item array accesses
// statically indexed (cmp/select chains in registers).
__global__ __launch_bounds__(256) void k_rank(const int* __restrict__ top_idx,
                                              int* __restrict__ dest,     // [2*N] k-major
                                              float* __restrict__ used) { // [NE]
    __shared__ int se[2 * N_TOK];   // 32 KB
    __shared__ int wsum[4][NE];
    const int t = threadIdx.x;
    const int lane = t & 63;
    const int wave = t >> 6;

    const int4* ti4 = (const int4*)top_idx;
    int4* se4 = (int4*)se;
#pragma unroll
    for (int i = 0; i < 8; ++i)
        se4[i * 256 + t] = ti4[i * 256 + t];
    __syncthreads();

    // pass 1: branchless per-thread histogram over 32 items
    int cnt[NE];
#pragma unroll
    for (int e = 0; e < NE; ++e) cnt[e] = 0;
    const int base = t * 32;
#pragma unroll
    for (int jj = 0; jj < 32; ++jj) {
        int v = se[base + jj];
#pragma unroll
        for (int e = 0; e < NE; ++e) cnt[e] += (v == e) ? 1 : 0;
    }

    // wave-inclusive scan per expert, then cross-wave combine via LDS
    int incl[NE];
#pragma unroll
    for (int e = 0; e < NE; ++e) {
        int s = cnt[e];
#pragma unroll
        for (int off = 1; off < 64; off <<= 1) {
            int u = __shfl_up(s, off, 64);
            if (lane >= off) s += u;
        }
        incl[e] = s;
        if (lane == 63) wsum[wave][e] = s;
    }
    __syncthreads();

    int excl[NE];
#pragma unroll
    for (int e = 0; e < NE; ++e) {
        int off = 0;
#pragma unroll
        for (int w = 0; w < 4; ++w)
            off += (w < wave) ? wsum[w][e] : 0;
        excl[e] = off + incl[e] - cnt[e];
    }
    if (t < NE) {
        int total = wsum[0][t] + wsum[1][t] + wsum[2][t] + wsum[3][t];
        used[t] = (float)min(total, CAP);
    }

    // pass 2: branchless rank assignment -> dest element index
    int run[NE];
#pragma unroll
    for (int e = 0; e < NE; ++e) run[e] = excl[e];
#pragma unroll
    for (int jj = 0; jj < 32; ++jj) {
        int j = base + jj;
        int v = se[j];
        int r = run[0];
#pragma unroll
        for (int e = 1; e < NE; ++e) r = (v == e) ? run[e] : r;
#pragma unroll
        for (int e = 0; e < NE; ++e) run[e] += (v == e) ? 1 : 0;
        dest[j] = (r < CAP) ? (v * CAP + r) : -1;
    }
}

// ---------------- Stage 3: sparse scatter over a memset-zeroed output ---------
// Output is 99.99% zeros; hipMemsetAsync (runtime fill kernel, ~6.3 TB/s) does
// the bulk zeroing. This kernel writes only the <=16384 nonzero elements plus
// the 8 used-capacity values. Top-1 and top-2 of a token are distinct experts,
// so the two writes of a token never collide.
__global__ __launch_bounds__(256) void k_scatter(const int* __restrict__ dest,
                                                 const float* __restrict__ top_p,
                                                 const float* __restrict__ used,
                                                 float* __restrict__ out) {
    const int j = blockIdx.x * 256 + threadIdx.x;   // [0, 2*N)
    if (blockIdx.x == 0 && threadIdx.x < NE) out[threadIdx.x] = used[threadIdx.x];

    const int d = dest[j];
    if (d >= 0) {
        const int n = j & (N_TOK - 1);
        const float w = top_p[j];
        out[8 + (size_t)n * EC + d]       = w;                       // cb_weight
        out[8 + NEC + (size_t)n * EC + d] = (w != 0.f) ? 1.f : 0.f;  // sec_mask
    }
}

extern "C" void kernel_launch(void* const* d_in, const int* in_sizes, int n_in,
                              void* d_out, int out_size, void* d_ws, size_t ws_size,
                              hipStream_t stream) {
    const float* x  = (const float*)d_in[0];
    const float* wg = (const float*)d_in[1];
    float* out = (float*)d_out;
    char* ws = (char*)d_ws;

    int*   top_idx = (int*)(ws);             // 8192 ints   (32 KB)
    float* top_p   = (float*)(ws + 32768);   // 8192 floats (32 KB)
    int*   dest    = (int*)(ws + 65536);     // 8192 ints   (32 KB)
    float* used    = (float*)(ws + 98304);   // 8 floats

    // Bulk-zero the logical output: 8 + 2*N*E*C floats = 335.5 MB.
    // Runs as the runtime's fillBufferAligned at ~6.3 TB/s (~53 us).
    hipMemsetAsync(out, 0, (size_t)(8 + 2 * NEC) * sizeof(float), stream);

    k_logits<<<N_TOK / 4, 256, 0, stream>>>(x, wg, top_idx, top_p);
    k_rank<<<1, 256, 0, stream>>>(top_idx, dest, used);
    k_scatter<<<2 * N_TOK / 256, 256, 0, stream>>>(dest, top_p, used, out);
}